// Round 2
// baseline (233.173 us; speedup 1.0000x reference)
//
#include <hip/hip_runtime.h>
#include <cstdint>
#include <cstddef>

#define DEV static __device__ __forceinline__

typedef __attribute__((ext_vector_type(8))) short bf16x8;   // 8 bf16 (4 VGPRs)
typedef __attribute__((ext_vector_type(4))) float f32x4;

constexpr int NB   = 64;     // batch
constexpr int NTOK = 197;    // tokens
constexpr int DIMC = 768;    // channels
constexpr int NH   = 12;     // heads
constexpr int HDIM = 64;     // head dim
constexpr int MTOK = NB * NTOK;   // 12608 rows
constexpr int QKVO = 3 * DIMC;    // 2304
constexpr int BH   = NB * NH;     // 768
constexpr int KROWS = 198;        // staged K rows (jrow clamped to 197)
constexpr int VTS   = 232;        // V^T row stride (464B, 16B-aligned)
constexpr int OBS   = 68;         // O-bounce row stride (136B)
constexpr int GM64  = MTOK / 64;  // 197 M-tiles (64-row, exact)

// ---- qkv geometry: 256x256 tile, BK=64, 8 waves, 2x64KB LDS, persistent pairs ----
constexpr int BM2  = 256;
constexpr int BN2  = 256;
constexpr int GM2  = (MTOK + BM2 - 1) / BM2;   // 50 (tile 49 has 64 live rows)
constexpr int GN2  = QKVO / BN2;               // 9
constexpr int NKT  = DIMC / 64;                // 12 K-tiles per tile
constexpr int TOT  = 2 * NKT;                  // 24 K-tiles per persistent block
constexpr int GRID_QKV = (GM2 * GN2) / 2;      // 225 blocks x 2 tiles
constexpr int BUFH = 32768;                    // ushorts per buffer (A 16K + B 16K)

DEV unsigned short f2bf(float f) {
  union { float f; uint32_t u; } v; v.f = f;
  uint32_t u = v.u;
  return (unsigned short)((u + 0x7FFFu + ((u >> 16) & 1u)) >> 16);  // RNE, finite
}

DEV uint32_t pack_bf2(float a, float b) {
  return (uint32_t)f2bf(a) | ((uint32_t)f2bf(b) << 16);
}

DEV f32x4 mfma16(bf16x8 a, bf16x8 b, f32x4 c) {
  return __builtin_amdgcn_mfma_f32_16x16x32_bf16(a, b, c, 0, 0, 0);
}

DEV void async_cp16(const unsigned short* g, unsigned short* l) {
  __builtin_amdgcn_global_load_lds(
      (__attribute__((address_space(1))) void*)g,
      (__attribute__((address_space(3))) void*)l, 16, 0, 0);
}

// supertile swizzle: groups of 16 M-tiles, N-major inside the group.
// pairs (2b, 2b+1) always share nt (same B panel) and are M-adjacent.
DEV void swizzle_idx(int lin, int gridM, int gridN, int& mt, int& nt) {
  int per = 16 * gridN;
  int sup = lin / per;
  int bm  = sup * 16;
  int Gm  = gridM - bm; if (Gm > 16) Gm = 16;
  int rem = lin - sup * per;
  nt = rem / Gm;
  mt = bm + (rem - nt * Gm);
}

// ---------------- f32 -> bf16 converts: one kernel, 4 float4/thread ----------------
constexpr int CVB1 = (MTOK * DIMC) / 4096;   // 2364
constexpr int CVB2 = (QKVO * DIMC) / 4096;   //  432
constexpr int CVB3 = (DIMC * DIMC) / 4096;   //  144
constexpr int CVNB = CVB1 + CVB2 + CVB3;     // 2940

__global__ void __launch_bounds__(256) cvt_all(const float* __restrict__ x,
                                               const float* __restrict__ wq,
                                               const float* __restrict__ wp,
                                               unsigned short* __restrict__ xb,
                                               unsigned short* __restrict__ wqb,
                                               unsigned short* __restrict__ wpb) {
  int blk = blockIdx.x;
  const float* s; unsigned short* d;
  if (blk < CVB1)               { s = x;  d = xb; }
  else if (blk < CVB1 + CVB2)   { s = wq; d = wqb; blk -= CVB1; }
  else                          { s = wp; d = wpb; blk -= CVB1 + CVB2; }
  size_t base = (size_t)blk * 4096 + (size_t)threadIdx.x * 4;
#pragma unroll
  for (int j = 0; j < 4; ++j) {
    size_t i = base + (size_t)j * 1024;
    float4 f = *(const float4*)(s + i);
    ushort4 o;
    o.x = f2bf(f.x); o.y = f2bf(f.y); o.z = f2bf(f.z); o.w = f2bf(f.w);
    *(ushort4*)(d + i) = o;
  }
}

// ---------------- QKV GEMM: persistent 2-tile, 4-phase counted-vmcnt pipeline --------
// Staging units (quadrant-shaped, match read regions):
//   A-qm unit: rows {qm*64..+63} U {128+qm*64..}, 16 KB, 2 loads/thread
//   B-qn unit: rows {wn*64+qn*32..+31 : wn 0..3}, 16 KB, 2 loads/thread
// Issue stream (steady, per ktg): P1:[A-qm1->ktg+1] P2:[B-qn1->ktg+1]
//   P3:[A-qm0->ktg+2] P4:[B-qn0->ktg+2]
// Split gates (exact ledger, incl. prologue & tails):
//   P1-end vmcnt(6): completes qm1/qn1 of ktg (needed P2/P3), leaves 6.
//   P4-end vmcnt(8): completes qm0/qn0 of ktg+1 (needed next P1), leaves 8.
// Pipeline runs continuously across the tile-0/tile-1 boundary (buffers keyed
// by ktg&1); tile-0 epilogue is emitted per-quadrant inside ktg==11's phases.
DEV void stage_A_qm(const unsigned short* A, unsigned short* lds,
                    int mbase, int k0, int qm, int tid) {
#pragma unroll
  for (int u = 0; u < 2; ++u) {
    int c = u * 512 + tid;
    int row = c >> 3, cc = c & 7;
    int arow = qm * 64 + (row & 63) + ((row >> 6) << 7);
    int gr = mbase + arow; gr = gr < MTOK ? gr : MTOK - 1;   // M tail clamp
    int gc = (cc ^ (arow & 7)) * 8;
    async_cp16(A + (size_t)gr * DIMC + k0 + gc, lds + arow * 64 + cc * 8);
  }
}

DEV void stage_B_qn(const unsigned short* Bw, unsigned short* lds,
                    int nbase, int k0, int qn, int tid) {
#pragma unroll
  for (int u = 0; u < 2; ++u) {
    int c = u * 512 + tid;
    int row = c >> 3, cc = c & 7;
    int brow = (row >> 5) * 64 + qn * 32 + (row & 31);
    int gc = (cc ^ (brow & 7)) * 8;
    async_cp16(Bw + (size_t)(nbase + brow) * DIMC + k0 + gc, lds + brow * 64 + cc * 8);
  }
}

template <int QM>
DEV void ldA(const unsigned short* Ac, int wm, int l16, int quad, bf16x8 (&af)[4][2]) {
#pragma unroll
  for (int mi = 0; mi < 4; ++mi)
#pragma unroll
    for (int kk = 0; kk < 2; ++kk) {
      int r = wm * 128 + QM * 64 + mi * 16 + l16;
      af[mi][kk] = *(const bf16x8*)(Ac + r * 64 + (((kk * 4 + quad) ^ (r & 7)) * 8));
    }
}

template <int QN>
DEV void ldB(const unsigned short* Bc, int wn, int l16, int quad, bf16x8 (&bf_)[2][2]) {
#pragma unroll
  for (int ni = 0; ni < 2; ++ni)
#pragma unroll
    for (int kk = 0; kk < 2; ++kk) {
      int r = wn * 64 + QN * 32 + ni * 16 + l16;
      bf_[ni][kk] = *(const bf16x8*)(Bc + r * 64 + (((kk * 4 + quad) ^ (r & 7)) * 8));
    }
}

template <int QM, int QN>
DEV void ph_mfma(bf16x8 (&af)[4][2], bf16x8 (&bf_)[2][2], f32x4 (&acc)[8][4]) {
  __builtin_amdgcn_s_setprio(1);
#pragma unroll
  for (int kk = 0; kk < 2; ++kk)
#pragma unroll
    for (int mi = 0; mi < 4; ++mi)
#pragma unroll
      for (int ni = 0; ni < 2; ++ni)
        acc[QM * 4 + mi][QN * 2 + ni] =
            mfma16(af[mi][kk], bf_[ni][kk], acc[QM * 4 + mi][QN * 2 + ni]);
  __builtin_amdgcn_s_setprio(0);
}

// store one C-quadrant, then zero its accumulators (pipeline keeps running)
template <int QM, int QN>
DEV void epi_quad(f32x4 (&acc)[8][4], unsigned short* __restrict__ qkv,
                  int mbase, int nbase, int wm, int wn, int l16, int quad) {
  const int oc32  = nbase + wn * 64 + QN * 32;   // 32-aligned -> uniform which/h
  const int which = oc32 / DIMC;
  const int h     = (oc32 % DIMC) / HDIM;
#pragma unroll
  for (int mi = 0; mi < 4; ++mi) {
    int t0 = mbase + wm * 128 + QM * 64 + mi * 16 + quad * 4;
#pragma unroll
    for (int r = 0; r < 4; ++r) {
      int t = t0 + r;
      if (t < MTOK) {
        int b = t / NTOK, n = t - b * NTOK;
        size_t base = ((size_t)((which * NB + b) * NH + h) * NTOK + n) * HDIM;
#pragma unroll
        for (int ni = 0; ni < 2; ++ni)
          qkv[base + QN * 32 + ni * 16 + l16] = f2bf(acc[QM * 4 + mi][QN * 2 + ni][r]);
      }
    }
  }
#pragma unroll
  for (int mi = 0; mi < 4; ++mi)
#pragma unroll
    for (int ni = 0; ni < 2; ++ni)
      acc[QM * 4 + mi][QN * 2 + ni] = {0.f, 0.f, 0.f, 0.f};
}

__global__ void __launch_bounds__(512, 2) gemm_qkv(const unsigned short* __restrict__ A,
                                                   const unsigned short* __restrict__ Bw,
                                                   unsigned short* __restrict__ qkv) {
  extern __shared__ unsigned short lds[];   // 131072 B: [buf][A 16K | B 16K] ushorts
  const int tid = threadIdx.x, lane = tid & 63, wave = tid >> 6;
  const int wm = wave & 1, wn = wave >> 1;        // 2M x 4N waves
  const int l16 = lane & 15, quad = lane >> 4;

  int mbs[2], nbs[2];
  {
    int mt, nt;
    swizzle_idx(blockIdx.x * 2,     GM2, GN2, mt, nt);
    mbs[0] = mt * BM2; nbs[0] = nt * BN2;
    swizzle_idx(blockIdx.x * 2 + 1, GM2, GN2, mt, nt);
    mbs[1] = mt * BM2; nbs[1] = nt * BN2;   // same nt as tile 0 (B panel shared)
  }

  f32x4 acc[8][4];
#pragma unroll
  for (int i = 0; i < 8; ++i)
#pragma unroll
    for (int j = 0; j < 4; ++j) acc[i][j] = {0.f, 0.f, 0.f, 0.f};

  unsigned short* A0 = lds;
  unsigned short* B0 = lds + 16384;
  unsigned short* A1 = lds + BUFH;
  unsigned short* B1 = lds + BUFH + 16384;

  // prologue: ktg0 fully + ktg1's (A-qm0, B-qn0); vmcnt(4) confirms ktg0,
  // leaves ktg1's qm0/qn0 in flight (steady-state invariant).
  stage_A_qm(A, A0, mbs[0], 0, 0, tid);
  stage_B_qn(Bw, B0, nbs[0], 0, 0, tid);
  stage_A_qm(A, A0, mbs[0], 0, 1, tid);
  stage_B_qn(Bw, B0, nbs[0], 0, 1, tid);
  stage_A_qm(A, A1, mbs[0], 64, 0, tid);
  stage_B_qn(Bw, B1, nbs[0], 64, 0, tid);
  asm volatile("s_waitcnt vmcnt(4)" ::: "memory");
  __builtin_amdgcn_s_barrier();

  bf16x8 af[4][2], b0[2][2], b1[2][2];

  for (int ktg = 0; ktg < TOT; ++ktg) {
    unsigned short* Ac = (ktg & 1) ? A1 : A0;
    unsigned short* Bc = (ktg & 1) ? B1 : B0;
    unsigned short* An = (ktg & 1) ? A0 : A1;
    unsigned short* Bn = (ktg & 1) ? B0 : B1;

    // P1: quadrant (0,0); stage A-qm1 -> ktg+1
    ldA<0>(Ac, wm, l16, quad, af);
    ldB<0>(Bc, wn, l16, quad, b0);
    if (ktg + 1 < TOT) {
      int tg = ktg + 1, t1 = tg >= NKT;
      stage_A_qm(A, An, mbs[t1], (tg - t1 * NKT) * 64, 1, tid);
    }
    __builtin_amdgcn_s_barrier();
    ph_mfma<0, 0>(af, b0, acc);
    if (ktg < TOT - 1) asm volatile("s_waitcnt vmcnt(6) lgkmcnt(0)" ::: "memory");
    else               asm volatile("s_waitcnt vmcnt(0) lgkmcnt(0)" ::: "memory");
    __builtin_amdgcn_s_barrier();
    if (ktg == NKT - 1) epi_quad<0, 0>(acc, qkv, mbs[0], nbs[0], wm, wn, l16, quad);

    // P2: quadrant (0,1) — reuse af; stage B-qn1 -> ktg+1
    ldB<1>(Bc, wn, l16, quad, b1);
    if (ktg + 1 < TOT) {
      int tg = ktg + 1, t1 = tg >= NKT;
      stage_B_qn(Bw, Bn, nbs[t1], (tg - t1 * NKT) * 64, 1, tid);
    }
    __builtin_amdgcn_s_barrier();
    ph_mfma<0, 1>(af, b1, acc);
    asm volatile("s_waitcnt lgkmcnt(0)" ::: "memory");
    __builtin_amdgcn_s_barrier();
    if (ktg == NKT - 1) epi_quad<0, 1>(acc, qkv, mbs[0], nbs[0], wm, wn, l16, quad);

    // P3: quadrant (1,0) — reuse b0; stage A-qm0 -> ktg+2
    ldA<1>(Ac, wm, l16, quad, af);
    if (ktg + 2 < TOT) {
      int tg = ktg + 2, t1 = tg >= NKT;
      stage_A_qm(A, Ac, mbs[t1], (tg - t1 * NKT) * 64, 0, tid);
    }
    __builtin_amdgcn_s_barrier();
    ph_mfma<1, 0>(af, b0, acc);
    asm volatile("s_waitcnt lgkmcnt(0)" ::: "memory");
    __builtin_amdgcn_s_barrier();
    if (ktg == NKT - 1) epi_quad<1, 0>(acc, qkv, mbs[0], nbs[0], wm, wn, l16, quad);

    // P4: quadrant (1,1) — reuse af + b1; stage B-qn0 -> ktg+2
    if (ktg + 2 < TOT) {
      int tg = ktg + 2, t1 = tg >= NKT;
      stage_B_qn(Bw, Bc, nbs[t1], (tg - t1 * NKT) * 64, 0, tid);
    }
    __builtin_amdgcn_s_barrier();
    ph_mfma<1, 1>(af, b1, acc);
    if (ktg < TOT - 2)       asm volatile("s_waitcnt vmcnt(8) lgkmcnt(0)" ::: "memory");
    else if (ktg == TOT - 2) asm volatile("s_waitcnt vmcnt(4) lgkmcnt(0)" ::: "memory");
    else                     asm volatile("s_waitcnt vmcnt(0) lgkmcnt(0)" ::: "memory");
    __builtin_amdgcn_s_barrier();
    if (ktg == NKT - 1) epi_quad<1, 1>(acc, qkv, mbs[0], nbs[0], wm, wn, l16, quad);
  }

  // tile-1 epilogue
  epi_quad<0, 0>(acc, qkv, mbs[1], nbs[1], wm, wn, l16, quad);
  epi_quad<0, 1>(acc, qkv, mbs[1], nbs[1], wm, wn, l16, quad);
  epi_quad<1, 0>(acc, qkv, mbs[1], nbs[1], wm, wn, l16, quad);
  epi_quad<1, 1>(acc, qkv, mbs[1], nbs[1], wm, wn, l16, quad);
}

// ---------------- Proj GEMM 64x128 tiles (+bias+residual, fp32 out) ----------------
__global__ void __launch_bounds__(256) gemm_proj(const unsigned short* __restrict__ A,
                                                 const unsigned short* __restrict__ Bw,
                                                 const float* __restrict__ bias,
                                                 const float* __restrict__ xres,
                                                 float* __restrict__ out) {
  __shared__ __align__(16) unsigned short As[64 * 64];    //  8 KB
  __shared__ __align__(16) unsigned short Bs[128 * 64];   // 16 KB
  const int tid = threadIdx.x, lane = tid & 63, wave = tid >> 6;
  const int wm = wave & 1, wn = wave >> 1;
  const int l16 = lane & 15, quad = lane >> 4;
  int mt, nt;
  swizzle_idx(blockIdx.x, GM64, DIMC / 128, mt, nt);
  const int mbase = mt * 64, nbase = nt * 128;   // MTOK = 197*64 exactly: no tail

  f32x4 acc[2][4];
#pragma unroll
  for (int i = 0; i < 2; ++i)
#pragma unroll
    for (int j = 0; j < 4; ++j) acc[i][j] = {0.f, 0.f, 0.f, 0.f};

  for (int k0 = 0; k0 < DIMC; k0 += 64) {
#pragma unroll
    for (int i = 0; i < 2; ++i) {          // A: 512 x 16B chunks
      int c = i * 256 + tid;
      int row = c >> 3, cc = c & 7;
      int gc = (cc ^ (row & 7)) * 8;
      async_cp16(A + (size_t)(mbase + row) * DIMC + k0 + gc, As + c * 8);
    }
#pragma unroll
    for (int i = 0; i < 4; ++i) {          // B: 1024 x 16B chunks
      int c = i * 256 + tid;
      int row = c >> 3, cc = c & 7;
      int gc = (cc ^ (row & 7)) * 8;
      async_cp16(Bw + (size_t)(nbase + row) * DIMC + k0 + gc, Bs + c * 8);
    }
    __syncthreads();
#pragma unroll
    for (int kk = 0; kk < 64; kk += 32) {
      const int cw = (kk >> 3) + quad;
      bf16x8 af[2], bfr[4];
#pragma unroll
      for (int mi = 0; mi < 2; ++mi) {
        int r = wm * 32 + mi * 16 + l16;
        af[mi] = *(const bf16x8*)(As + r * 64 + (cw ^ (r & 7)) * 8);
      }
#pragma unroll
      for (int ni = 0; ni < 4; ++ni) {
        int r = wn * 64 + ni * 16 + l16;
        bfr[ni] = *(const bf16x8*)(Bs + r * 64 + (cw ^ (r & 7)) * 8);
      }
#pragma unroll
      for (int mi = 0; mi < 2; ++mi)
#pragma unroll
        for (int ni = 0; ni < 4; ++ni)
          acc[mi][ni] = mfma16(af[mi], bfr[ni], acc[mi][ni]);
    }
    __syncthreads();
  }

  const int oc = nbase + wn * 64;
#pragma unroll
  for (int mi = 0; mi < 2; ++mi) {
    int t0 = mbase + wm * 32 + mi * 16 + quad * 4;
#pragma unroll
    for (int r = 0; r < 4; ++r) {
      int t = t0 + r;                      // always < MTOK (exact tiling)
      size_t rowb = (size_t)t * DIMC;
#pragma unroll
      for (int ni = 0; ni < 4; ++ni) {
        int o = oc + ni * 16 + l16;
        out[rowb + o] = acc[mi][ni][r] + bias[o] + xres[rowb + o];
      }
    }
  }
}

// ---------------- fused attention: 768 blocks x 1 head (R6-proven) ----------------
__global__ void __launch_bounds__(256, 2) attn_fused(const unsigned short* __restrict__ qkv,
                                                     const float* __restrict__ scale,
                                                     unsigned short* __restrict__ aout) {
  __shared__ __align__(16) unsigned short Ks[KROWS * 64];        // 25344 B
  __shared__ __align__(16) unsigned short Vt[HDIM * VTS];        // 29696 B
  __shared__ __align__(16) unsigned short Ob[4 * 16 * OBS];      //  8704 B

  const int tid = threadIdx.x, lane = tid & 63, wave = tid >> 6;
  const int l16 = lane & 15, quad = lane >> 4;
  const int bh = blockIdx.x;
  const int b = bh / NH, h = bh - b * NH;

  const unsigned short* qg = qkv + (size_t)bh * (NTOK * HDIM);
  const unsigned short* kg = qkv + (size_t)(BH + bh) * (NTOK * HDIM);
  const unsigned short* vg = qkv + (size_t)(2 * BH + bh) * (NTOK * HDIM);
  const float sc = scale[h];

  // stage K via DMA: rows 0..197
#pragma unroll
  for (int i = 0; i < 7; ++i) {
    int c = i * 256 + tid;
    if (c < KROWS * 8) {
      int row = c >> 3, cc = c & 7;
      async_cp16(kg + (size_t)row * 64 + ((cc ^ (row & 7)) * 8), Ks + c * 8);
    }
  }
  // build V^T: coalesced 128B row reads + b128 writes at stride VTS
  {
    const int dcol = tid & 63;
    const int slab = tid >> 6;
#pragma unroll
    for (int p = 0; p < 7; ++p) {
      int n0 = p * 32 + slab * 8;
      union { unsigned short us[8]; bf16x8 v; } tr;
#pragma unroll
      for (int i = 0; i < 8; ++i) {
        int n = n0 + i; n = n > NTOK - 1 ? NTOK - 1 : n;
        tr.us[i] = vg[(size_t)n * HDIM + dcol];
      }
      *(bf16x8*)(Vt + dcol * VTS + n0) = tr.v;
    }
  }
  __syncthreads();

  const int srcA  = l16 + ((quad & 1) << 5);
  const int srcB  = srcA + 16;
  const int stsel = quad >> 1;
  unsigned short* ob = Ob + wave * (16 * OBS);

  for (int mt = wave; mt < 13; mt += 4) {
    int qr = mt * 16 + l16; if (qr > NTOK - 1) qr = NTOK - 1;
    bf16x8 qb0 = *(const bf16x8*)(qg + (size_t)qr * 64 + quad * 8);
    bf16x8 qb1 = *(const bf16x8*)(qg + (size_t)qr * 64 + 32 + quad * 8);
    const int mg = mt * 16 + l16;

    // batched S^T = K.Q^T (26 MFMAs; jc=6,st=1 keys all masked)
    f32x4 s[7][2];
#pragma unroll
    for (int jc = 0; jc < 7; ++jc)
#pragma unroll
      for (int st = 0; st < 2; ++st) {
        if (jc == 6 && st == 1) { s[6][1] = {0.f, 0.f, 0.f, 0.f}; continue; }
        int jrow = (jc * 2 + st) * 16 + l16;
        jrow = jrow > NTOK ? NTOK : jrow;
        const unsigned short* kr = Ks + jrow * 64;
        bf16x8 ka0 = *(const bf16x8*)(kr + (quad       ^ (jrow & 7)) * 8);
        bf16x8 ka1 = *(const bf16x8*)(kr + ((4 + quad) ^ (jrow & 7)) * 8);
        f32x4 t = {0.f, 0.f, 0.f, 0.f};
        t = mfma16(ka0, qb0, t);
        t = mfma16(ka1, qb1, t);
        s[jc][st] = t;
      }

    // softmax over keys (row = l16)
    float cmax = -1e30f;
#pragma unroll
    for (int jc = 0; jc < 7; ++jc)
#pragma unroll
      for (int st = 0; st < 2; ++st)
#pragma unroll
        for (int r = 0; r < 4; ++r) {
          int jg = jc * 32 + st * 16 + quad * 4 + r;
          float v = s[jc][st][r] * sc;
          v = (jg >= NTOK || jg == mg) ? -1e30f : v;
          s[jc][st][r] = v;
          cmax = fmaxf(cmax, v);
        }
    cmax = fmaxf(cmax, __shfl_xor(cmax, 16));
    cmax = fmaxf(cmax, __shfl_xor(cmax, 32));
    float psum = 0.f;
#pragma unroll
    for (int jc = 0; jc < 7; ++jc)
#pragma unroll
      for (int st = 0; st < 2; ++st)
#pragma unroll
        for (int r = 0; r < 4; ++r) {
          float e = __expf(s[jc][st][r] - cmax);
          psum += e;
          s[jc][st][r] = e;
        }
    psum += __shfl_xor(psum, 16);
    psum += __shfl_xor(psum, 32);
    const float inv = 1.0f / psum;

    // PV: O^T = V^T.P^T; P^T B-frags via shfl, V^T b128 from LDS
    f32x4 oacc[4];
#pragma unroll
    for (int dt = 0; dt < 4; ++dt) oacc[dt] = {0.f, 0.f, 0.f, 0.f};

#pragma unroll
    for (int jc = 0; jc < 7; ++jc) {
      uint32_t u0 = pack_bf2(s[jc][0][0], s[jc][0][1]);
      uint32_t v0 = pack_bf2(s[jc][0][2], s[jc][0][3]);
      uint32_t u1 = pack_bf2(s[jc][1][0], s[jc][1][1]);
      uint32_t v1 = pack_bf2(s[jc][1][2], s[jc][1][3]);
      uint32_t au0 = (uint32_t)__shfl((int)u0, srcA);
      uint32_t av0 = (uint32_t)__shfl((int)v0, srcA);
      uint32_t au1 = (uint32_t)__shfl((int)u1, srcA);
      uint32_t av1 = (uint32_t)__shfl((int)v1, srcA);
      uint32_t bu0 = (uint32_t)__shfl((int)u0, srcB);
      uint32_t bv0 = (uint32_t)__shfl((int)v0, srcB);
      uint32_t bu1 = (uint32_t)__shfl((int)u1, srcB);
      uint32_t bv1 = (uint32_t)__shfl((int)v1, srcB);
      union { uint32_t u[4]; bf16x8 v; } pb;
      pb.u[0] = stsel ? au1 : au0;
      pb.u[1] = stsel ? av1 : av0;
      pb.u[2] = stsel ? bu1 : bu0;
      pb.u[3] = stsel ? bv1 : bv0;
#pragma unroll
      for (int dt = 0; dt < 4; ++dt) {
        bf16x8 va = *(const bf16x8*)(Vt + (dt * 16 + l16) * VTS +
                                     jc * 32 + quad * 8);
        oacc[dt] = mfma16(va, pb.v, oacc[dt]);
      }
    }

    // O store via per-wave LDS bounce -> full 128B line stores
#pragma unroll
    for (int dt = 0; dt < 4; ++dt) {
      ushort4 pk;
      pk.x = f2bf(oacc[dt][0] * inv);
      pk.y = f2bf(oacc[dt][1] * inv);
      pk.z = f2bf(oacc[dt][2] * inv);
      pk.w = f2bf(oacc[dt][3] * inv);
      *(ushort4*)(ob + l16 * OBS + dt * 16 + quad * 4) = pk;
    }
    __asm__ __volatile__("s_waitcnt lgkmcnt(0)" ::: "memory");
#pragma unroll
    for (int rnd = 0; rnd < 4; ++rnd) {
      int q   = rnd * 4 + (lane >> 4);
      int o8  = lane & 15;
      uint2 d8 = *(const uint2*)(ob + q * OBS + o8 * 4);
      int qrow = mt * 16 + q;
      if (qrow < NTOK) {
        size_t obase = (size_t)(b * NTOK + qrow) * DIMC + h * HDIM;
        *(uint2*)(aout + obase + o8 * 4) = d8;
      }
    }
  }
}

// ---------------- launcher ----------------
extern "C" void kernel_launch(void* const* d_in, const int* in_sizes, int n_in,
                              void* d_out, int out_size, void* d_ws, size_t ws_size,
                              hipStream_t stream) {
  const float* x     = (const float*)d_in[0];
  const float* scale = (const float*)d_in[1];
  const float* wqkv  = (const float*)d_in[2];
  const float* wproj = (const float*)d_in[3];
  const float* bproj = (const float*)d_in[4];
  float* out = (float*)d_out;

  // ws layout (ushort), ~82.2 MB (R6-proven). attb aliases xb.
  unsigned short* xb   = (unsigned short*)d_ws;
  unsigned short* wqb  = xb  + (size_t)MTOK * DIMC;
  unsigned short* wpb  = wqb + (size_t)QKVO * DIMC;
  unsigned short* qkvb = wpb + (size_t)DIMC * DIMC;
  unsigned short* attb = xb;                          // alias

  static bool qkv_attr_set = false;
  if (!qkv_attr_set) {
    hipFuncSetAttribute(reinterpret_cast<const void*>(gemm_qkv),
                        hipFuncAttributeMaxDynamicSharedMemorySize, 131072);
    qkv_attr_set = true;
  }

  cvt_all<<<CVNB, 256, 0, stream>>>(x, wqkv, wproj, xb, wqb, wpb);
  gemm_qkv<<<GRID_QKV, 512, 131072, stream>>>(xb, wqb, qkvb);
  attn_fused<<<BH, 256, 0, stream>>>(qkvb, scale, attb);
  gemm_proj<<<GM64 * (DIMC / 128), 256, 0, stream>>>(attb, wpb, bproj, x, out);
}

// Round 3
// 209.306 us; speedup vs baseline: 1.1140x; 1.1140x over previous
//
#include <hip/hip_runtime.h>
#include <cstdint>
#include <cstddef>

#define DEV static __device__ __forceinline__

typedef __attribute__((ext_vector_type(8))) short bf16x8;   // 8 bf16 (4 VGPRs)
typedef __attribute__((ext_vector_type(4))) float f32x4;

constexpr int NB   = 64;     // batch
constexpr int NTOK = 197;    // tokens
constexpr int DIMC = 768;    // channels
constexpr int NH   = 12;     // heads
constexpr int HDIM = 64;     // head dim
constexpr int MTOK = NB * NTOK;   // 12608 rows
constexpr int QKVO = 3 * DIMC;    // 2304
constexpr int BH   = NB * NH;     // 768
constexpr int KROWS = 198;        // staged K rows (jrow clamped to 197)
constexpr int VTS   = 232;        // V^T row stride (464B, 16B-aligned)
constexpr int OBS   = 68;         // O-bounce row stride (136B)
constexpr int GM64  = MTOK / 64;  // 197 M-tiles (64-row, exact)

// ---- qkv geometry: 256x256 tile, BK=64, 8 waves, 2x64KB LDS ----
constexpr int BM2  = 256;
constexpr int BN2  = 256;
constexpr int GM2  = (MTOK + BM2 - 1) / BM2;   // 50 (tile 49 has 64 live rows)
constexpr int GN2  = QKVO / BN2;               // 9
constexpr int NKT  = DIMC / 64;                // 12 K-tiles
constexpr int BUFH = 32768;                    // ushorts per buffer (A 16K + B 16K)

DEV unsigned short f2bf(float f) {
  union { float f; uint32_t u; } v; v.f = f;
  uint32_t u = v.u;
  return (unsigned short)((u + 0x7FFFu + ((u >> 16) & 1u)) >> 16);  // RNE, finite
}

DEV uint32_t pack_bf2(float a, float b) {
  return (uint32_t)f2bf(a) | ((uint32_t)f2bf(b) << 16);
}

DEV f32x4 mfma16(bf16x8 a, bf16x8 b, f32x4 c) {
  return __builtin_amdgcn_mfma_f32_16x16x32_bf16(a, b, c, 0, 0, 0);
}

DEV void async_cp16(const unsigned short* g, unsigned short* l) {
  __builtin_amdgcn_global_load_lds(
      (__attribute__((address_space(1))) void*)g,
      (__attribute__((address_space(3))) void*)l, 16, 0, 0);
}

// supertile swizzle: groups of 16 M-tiles, N-major inside the group.
DEV void swizzle_idx(int lin, int gridM, int gridN, int& mt, int& nt) {
  int per = 16 * gridN;
  int sup = lin / per;
  int bm  = sup * 16;
  int Gm  = gridM - bm; if (Gm > 16) Gm = 16;
  int rem = lin - sup * per;
  nt = rem / Gm;
  mt = bm + (rem - nt * Gm);
}

// ---------------- f32 -> bf16 converts: one kernel, 4 float4/thread ----------------
constexpr int CVB1 = (MTOK * DIMC) / 4096;   // 2364
constexpr int CVB2 = (QKVO * DIMC) / 4096;   //  432
constexpr int CVB3 = (DIMC * DIMC) / 4096;   //  144
constexpr int CVNB = CVB1 + CVB2 + CVB3;     // 2940

__global__ void __launch_bounds__(256) cvt_all(const float* __restrict__ x,
                                               const float* __restrict__ wq,
                                               const float* __restrict__ wp,
                                               unsigned short* __restrict__ xb,
                                               unsigned short* __restrict__ wqb,
                                               unsigned short* __restrict__ wpb) {
  int blk = blockIdx.x;
  const float* s; unsigned short* d;
  if (blk < CVB1)               { s = x;  d = xb; }
  else if (blk < CVB1 + CVB2)   { s = wq; d = wqb; blk -= CVB1; }
  else                          { s = wp; d = wpb; blk -= CVB1 + CVB2; }
  size_t base = (size_t)blk * 4096 + (size_t)threadIdx.x * 4;
#pragma unroll
  for (int j = 0; j < 4; ++j) {
    size_t i = base + (size_t)j * 1024;
    float4 f = *(const float4*)(s + i);
    ushort4 o;
    o.x = f2bf(f.x); o.y = f2bf(f.y); o.z = f2bf(f.z); o.w = f2bf(f.w);
    *(ushort4*)(d + i) = o;
  }
}

// ---------------- QKV GEMM: 256x256 tile, barrier-minimal dbuf pipeline ----------------
// R3: intra-K-tile barriers removed. Staging is depth-1 (all 4 units of kt+1
// issued at kt start, into the NEXT buffer only -> no intra-tile WAR hazard).
// Required sync = ONE {vmcnt(0); s_barrier} per K-tile boundary:
//   - my ds_reads of Ac/Bc are complete before I pass the barrier (MFMA consumed them);
//   - all waves' stages into An/Bn are complete (each waited its own vmcnt(0));
//   -> after barrier, next K-tile may read An/Bn and stage into Ac/Bc. QED.
// vmcnt(0) is cheap here: the 8 loads are issued a full K-tile (~4000 cyc) before
// the wait (HBM latency ~900) — unlike m97's drain-in-short-window pathology.
// Without lockstep phase barriers, waves slip and ds_reads hide under MFMAs.
DEV void stage_A_qm(const unsigned short* A, unsigned short* lds,
                    int mbase, int k0, int qm, int tid) {
#pragma unroll
  for (int u = 0; u < 2; ++u) {
    int c = u * 512 + tid;
    int row = c >> 3, cc = c & 7;
    int arow = qm * 64 + (row & 63) + ((row >> 6) << 7);
    int gr = mbase + arow; gr = gr < MTOK ? gr : MTOK - 1;   // M tail clamp
    int gc = (cc ^ (arow & 7)) * 8;
    async_cp16(A + (size_t)gr * DIMC + k0 + gc, lds + arow * 64 + cc * 8);
  }
}

DEV void stage_B_qn(const unsigned short* Bw, unsigned short* lds,
                    int nbase, int k0, int qn, int tid) {
#pragma unroll
  for (int u = 0; u < 2; ++u) {
    int c = u * 512 + tid;
    int row = c >> 3, cc = c & 7;
    int brow = (row >> 5) * 64 + qn * 32 + (row & 31);
    int gc = (cc ^ (brow & 7)) * 8;
    async_cp16(Bw + (size_t)(nbase + brow) * DIMC + k0 + gc, lds + brow * 64 + cc * 8);
  }
}

template <int QM>
DEV void ldA(const unsigned short* Ac, int wm, int l16, int quad, bf16x8 (&af)[4][2]) {
#pragma unroll
  for (int mi = 0; mi < 4; ++mi)
#pragma unroll
    for (int kk = 0; kk < 2; ++kk) {
      int r = wm * 128 + QM * 64 + mi * 16 + l16;
      af[mi][kk] = *(const bf16x8*)(Ac + r * 64 + (((kk * 4 + quad) ^ (r & 7)) * 8));
    }
}

template <int QN>
DEV void ldB(const unsigned short* Bc, int wn, int l16, int quad, bf16x8 (&bf_)[2][2]) {
#pragma unroll
  for (int ni = 0; ni < 2; ++ni)
#pragma unroll
    for (int kk = 0; kk < 2; ++kk) {
      int r = wn * 64 + QN * 32 + ni * 16 + l16;
      bf_[ni][kk] = *(const bf16x8*)(Bc + r * 64 + (((kk * 4 + quad) ^ (r & 7)) * 8));
    }
}

template <int QM, int QN>
DEV void ph_mfma(bf16x8 (&af)[4][2], bf16x8 (&bf_)[2][2], f32x4 (&acc)[8][4]) {
  __builtin_amdgcn_s_setprio(1);
#pragma unroll
  for (int kk = 0; kk < 2; ++kk)
#pragma unroll
    for (int mi = 0; mi < 4; ++mi)
#pragma unroll
      for (int ni = 0; ni < 2; ++ni)
        acc[QM * 4 + mi][QN * 2 + ni] =
            mfma16(af[mi][kk], bf_[ni][kk], acc[QM * 4 + mi][QN * 2 + ni]);
  __builtin_amdgcn_s_setprio(0);
}

__global__ void __launch_bounds__(512, 2) gemm_qkv(const unsigned short* __restrict__ A,
                                                   const unsigned short* __restrict__ Bw,
                                                   unsigned short* __restrict__ qkv) {
  extern __shared__ unsigned short lds[];   // 131072 B: [buf][A 16K | B 16K] ushorts
  const int tid = threadIdx.x, lane = tid & 63, wave = tid >> 6;
  const int wm = wave & 1, wn = wave >> 1;        // 2M x 4N waves
  const int l16 = lane & 15, quad = lane >> 4;
  int mt, nt;
  swizzle_idx(blockIdx.x, GM2, GN2, mt, nt);
  const int mbase = mt * BM2, nbase = nt * BN2;

  f32x4 acc[8][4];
#pragma unroll
  for (int i = 0; i < 8; ++i)
#pragma unroll
    for (int j = 0; j < 4; ++j) acc[i][j] = {0.f, 0.f, 0.f, 0.f};

  unsigned short* A0 = lds;
  unsigned short* B0 = lds + 16384;
  unsigned short* A1 = lds + BUFH;
  unsigned short* B1 = lds + BUFH + 16384;

  // prologue: stage kt0 fully into buf0, drain, barrier
  stage_A_qm(A, A0, mbase, 0, 0, tid);
  stage_A_qm(A, A0, mbase, 0, 1, tid);
  stage_B_qn(Bw, B0, nbase, 0, 0, tid);
  stage_B_qn(Bw, B0, nbase, 0, 1, tid);
  asm volatile("s_waitcnt vmcnt(0)" ::: "memory");
  __builtin_amdgcn_s_barrier();

  bf16x8 af[4][2], b0[2][2], b1[2][2];

  for (int kt = 0; kt < NKT; ++kt) {
    unsigned short* Ac = (kt & 1) ? A1 : A0;
    unsigned short* Bc = (kt & 1) ? B1 : B0;
    unsigned short* An = (kt & 1) ? A0 : A1;
    unsigned short* Bn = (kt & 1) ? B0 : B1;

    // issue next K-tile's staging up front (next buffer only)
    if (kt + 1 < NKT) {
      int k0n = (kt + 1) * 64;
      stage_A_qm(A, An, mbase, k0n, 0, tid);
      stage_A_qm(A, An, mbase, k0n, 1, tid);
      stage_B_qn(Bw, Bn, nbase, k0n, 0, tid);
      stage_B_qn(Bw, Bn, nbase, k0n, 1, tid);
    }

    // free-running compute: ds_reads hide under MFMAs (no phase barriers)
    ldA<0>(Ac, wm, l16, quad, af);
    ldB<0>(Bc, wn, l16, quad, b0);
    ph_mfma<0, 0>(af, b0, acc);
    ldB<1>(Bc, wn, l16, quad, b1);
    ph_mfma<0, 1>(af, b1, acc);
    ldA<1>(Ac, wm, l16, quad, af);
    ph_mfma<1, 0>(af, b0, acc);
    ph_mfma<1, 1>(af, b1, acc);

    // K-tile boundary: my stages landed + everyone done reading cur buf
    if (kt + 1 < NKT) {
      asm volatile("s_waitcnt vmcnt(0)" ::: "memory");
      __builtin_amdgcn_s_barrier();
    }
  }

  // epilogue: scatter to qkv bf16 [3][B][H][N][HD]
  const int oc64  = nbase + wn * 64;   // 64-aligned -> uniform which/h per wave
  const int which = oc64 / DIMC;
  const int h     = (oc64 % DIMC) / HDIM;
#pragma unroll
  for (int mi8 = 0; mi8 < 8; ++mi8) {
    int t0 = mbase + wm * 128 + mi8 * 16 + quad * 4;
#pragma unroll
    for (int r = 0; r < 4; ++r) {
      int t = t0 + r;
      if (t < MTOK) {
        int b = t / NTOK, n = t - b * NTOK;
        size_t base = ((size_t)((which * NB + b) * NH + h) * NTOK + n) * HDIM;
#pragma unroll
        for (int ni = 0; ni < 4; ++ni)
          qkv[base + ni * 16 + l16] = f2bf(acc[mi8][ni][r]);
      }
    }
  }
}

// ---------------- Proj GEMM 64x128 tiles (+bias+residual, fp32 out) ----------------
__global__ void __launch_bounds__(256) gemm_proj(const unsigned short* __restrict__ A,
                                                 const unsigned short* __restrict__ Bw,
                                                 const float* __restrict__ bias,
                                                 const float* __restrict__ xres,
                                                 float* __restrict__ out) {
  __shared__ __align__(16) unsigned short As[64 * 64];    //  8 KB
  __shared__ __align__(16) unsigned short Bs[128 * 64];   // 16 KB
  const int tid = threadIdx.x, lane = tid & 63, wave = tid >> 6;
  const int wm = wave & 1, wn = wave >> 1;
  const int l16 = lane & 15, quad = lane >> 4;
  int mt, nt;
  swizzle_idx(blockIdx.x, GM64, DIMC / 128, mt, nt);
  const int mbase = mt * 64, nbase = nt * 128;   // MTOK = 197*64 exactly: no tail

  f32x4 acc[2][4];
#pragma unroll
  for (int i = 0; i < 2; ++i)
#pragma unroll
    for (int j = 0; j < 4; ++j) acc[i][j] = {0.f, 0.f, 0.f, 0.f};

  for (int k0 = 0; k0 < DIMC; k0 += 64) {
#pragma unroll
    for (int i = 0; i < 2; ++i) {          // A: 512 x 16B chunks
      int c = i * 256 + tid;
      int row = c >> 3, cc = c & 7;
      int gc = (cc ^ (row & 7)) * 8;
      async_cp16(A + (size_t)(mbase + row) * DIMC + k0 + gc, As + c * 8);
    }
#pragma unroll
    for (int i = 0; i < 4; ++i) {          // B: 1024 x 16B chunks
      int c = i * 256 + tid;
      int row = c >> 3, cc = c & 7;
      int gc = (cc ^ (row & 7)) * 8;
      async_cp16(Bw + (size_t)(nbase + row) * DIMC + k0 + gc, Bs + c * 8);
    }
    __syncthreads();
#pragma unroll
    for (int kk = 0; kk < 64; kk += 32) {
      const int cw = (kk >> 3) + quad;
      bf16x8 af[2], bfr[4];
#pragma unroll
      for (int mi = 0; mi < 2; ++mi) {
        int r = wm * 32 + mi * 16 + l16;
        af[mi] = *(const bf16x8*)(As + r * 64 + (cw ^ (r & 7)) * 8);
      }
#pragma unroll
      for (int ni = 0; ni < 4; ++ni) {
        int r = wn * 64 + ni * 16 + l16;
        bfr[ni] = *(const bf16x8*)(Bs + r * 64 + (cw ^ (r & 7)) * 8);
      }
#pragma unroll
      for (int mi = 0; mi < 2; ++mi)
#pragma unroll
        for (int ni = 0; ni < 4; ++ni)
          acc[mi][ni] = mfma16(af[mi], bfr[ni], acc[mi][ni]);
    }
    __syncthreads();
  }

  const int oc = nbase + wn * 64;
#pragma unroll
  for (int mi = 0; mi < 2; ++mi) {
    int t0 = mbase + wm * 32 + mi * 16 + quad * 4;
#pragma unroll
    for (int r = 0; r < 4; ++r) {
      int t = t0 + r;                      // always < MTOK (exact tiling)
      size_t rowb = (size_t)t * DIMC;
#pragma unroll
      for (int ni = 0; ni < 4; ++ni) {
        int o = oc + ni * 16 + l16;
        out[rowb + o] = acc[mi][ni][r] + bias[o] + xres[rowb + o];
      }
    }
  }
}

// ---------------- fused attention: 768 blocks x 1 head (R6-proven) ----------------
__global__ void __launch_bounds__(256, 2) attn_fused(const unsigned short* __restrict__ qkv,
                                                     const float* __restrict__ scale,
                                                     unsigned short* __restrict__ aout) {
  __shared__ __align__(16) unsigned short Ks[KROWS * 64];        // 25344 B
  __shared__ __align__(16) unsigned short Vt[HDIM * VTS];        // 29696 B
  __shared__ __align__(16) unsigned short Ob[4 * 16 * OBS];      //  8704 B

  const int tid = threadIdx.x, lane = tid & 63, wave = tid >> 6;
  const int l16 = lane & 15, quad = lane >> 4;
  const int bh = blockIdx.x;
  const int b = bh / NH, h = bh - b * NH;

  const unsigned short* qg = qkv + (size_t)bh * (NTOK * HDIM);
  const unsigned short* kg = qkv + (size_t)(BH + bh) * (NTOK * HDIM);
  const unsigned short* vg = qkv + (size_t)(2 * BH + bh) * (NTOK * HDIM);
  const float sc = scale[h];

  // stage K via DMA: rows 0..197
#pragma unroll
  for (int i = 0; i < 7; ++i) {
    int c = i * 256 + tid;
    if (c < KROWS * 8) {
      int row = c >> 3, cc = c & 7;
      async_cp16(kg + (size_t)row * 64 + ((cc ^ (row & 7)) * 8), Ks + c * 8);
    }
  }
  // build V^T: coalesced 128B row reads + b128 writes at stride VTS
  {
    const int dcol = tid & 63;
    const int slab = tid >> 6;
#pragma unroll
    for (int p = 0; p < 7; ++p) {
      int n0 = p * 32 + slab * 8;
      union { unsigned short us[8]; bf16x8 v; } tr;
#pragma unroll
      for (int i = 0; i < 8; ++i) {
        int n = n0 + i; n = n > NTOK - 1 ? NTOK - 1 : n;
        tr.us[i] = vg[(size_t)n * HDIM + dcol];
      }
      *(bf16x8*)(Vt + dcol * VTS + n0) = tr.v;
    }
  }
  __syncthreads();

  const int srcA  = l16 + ((quad & 1) << 5);
  const int srcB  = srcA + 16;
  const int stsel = quad >> 1;
  unsigned short* ob = Ob + wave * (16 * OBS);

  for (int mt = wave; mt < 13; mt += 4) {
    int qr = mt * 16 + l16; if (qr > NTOK - 1) qr = NTOK - 1;
    bf16x8 qb0 = *(const bf16x8*)(qg + (size_t)qr * 64 + quad * 8);
    bf16x8 qb1 = *(const bf16x8*)(qg + (size_t)qr * 64 + 32 + quad * 8);
    const int mg = mt * 16 + l16;

    // batched S^T = K.Q^T (26 MFMAs; jc=6,st=1 keys all masked)
    f32x4 s[7][2];
#pragma unroll
    for (int jc = 0; jc < 7; ++jc)
#pragma unroll
      for (int st = 0; st < 2; ++st) {
        if (jc == 6 && st == 1) { s[6][1] = {0.f, 0.f, 0.f, 0.f}; continue; }
        int jrow = (jc * 2 + st) * 16 + l16;
        jrow = jrow > NTOK ? NTOK : jrow;
        const unsigned short* kr = Ks + jrow * 64;
        bf16x8 ka0 = *(const bf16x8*)(kr + (quad       ^ (jrow & 7)) * 8);
        bf16x8 ka1 = *(const bf16x8*)(kr + ((4 + quad) ^ (jrow & 7)) * 8);
        f32x4 t = {0.f, 0.f, 0.f, 0.f};
        t = mfma16(ka0, qb0, t);
        t = mfma16(ka1, qb1, t);
        s[jc][st] = t;
      }

    // softmax over keys (row = l16)
    float cmax = -1e30f;
#pragma unroll
    for (int jc = 0; jc < 7; ++jc)
#pragma unroll
      for (int st = 0; st < 2; ++st)
#pragma unroll
        for (int r = 0; r < 4; ++r) {
          int jg = jc * 32 + st * 16 + quad * 4 + r;
          float v = s[jc][st][r] * sc;
          v = (jg >= NTOK || jg == mg) ? -1e30f : v;
          s[jc][st][r] = v;
          cmax = fmaxf(cmax, v);
        }
    cmax = fmaxf(cmax, __shfl_xor(cmax, 16));
    cmax = fmaxf(cmax, __shfl_xor(cmax, 32));
    float psum = 0.f;
#pragma unroll
    for (int jc = 0; jc < 7; ++jc)
#pragma unroll
      for (int st = 0; st < 2; ++st)
#pragma unroll
        for (int r = 0; r < 4; ++r) {
          float e = __expf(s[jc][st][r] - cmax);
          psum += e;
          s[jc][st][r] = e;
        }
    psum += __shfl_xor(psum, 16);
    psum += __shfl_xor(psum, 32);
    const float inv = 1.0f / psum;

    // PV: O^T = V^T.P^T; P^T B-frags via shfl, V^T b128 from LDS
    f32x4 oacc[4];
#pragma unroll
    for (int dt = 0; dt < 4; ++dt) oacc[dt] = {0.f, 0.f, 0.f, 0.f};

#pragma unroll
    for (int jc = 0; jc < 7; ++jc) {
      uint32_t u0 = pack_bf2(s[jc][0][0], s[jc][0][1]);
      uint32_t v0 = pack_bf2(s[jc][0][2], s[jc][0][3]);
      uint32_t u1 = pack_bf2(s[jc][1][0], s[jc][1][1]);
      uint32_t v1 = pack_bf2(s[jc][1][2], s[jc][1][3]);
      uint32_t au0 = (uint32_t)__shfl((int)u0, srcA);
      uint32_t av0 = (uint32_t)__shfl((int)v0, srcA);
      uint32_t au1 = (uint32_t)__shfl((int)u1, srcA);
      uint32_t av1 = (uint32_t)__shfl((int)v1, srcA);
      uint32_t bu0 = (uint32_t)__shfl((int)u0, srcB);
      uint32_t bv0 = (uint32_t)__shfl((int)v0, srcB);
      uint32_t bu1 = (uint32_t)__shfl((int)u1, srcB);
      uint32_t bv1 = (uint32_t)__shfl((int)v1, srcB);
      union { uint32_t u[4]; bf16x8 v; } pb;
      pb.u[0] = stsel ? au1 : au0;
      pb.u[1] = stsel ? av1 : av0;
      pb.u[2] = stsel ? bu1 : bu0;
      pb.u[3] = stsel ? bv1 : bv0;
#pragma unroll
      for (int dt = 0; dt < 4; ++dt) {
        bf16x8 va = *(const bf16x8*)(Vt + (dt * 16 + l16) * VTS +
                                     jc * 32 + quad * 8);
        oacc[dt] = mfma16(va, pb.v, oacc[dt]);
      }
    }

    // O store via per-wave LDS bounce -> full 128B line stores
#pragma unroll
    for (int dt = 0; dt < 4; ++dt) {
      ushort4 pk;
      pk.x = f2bf(oacc[dt][0] * inv);
      pk.y = f2bf(oacc[dt][1] * inv);
      pk.z = f2bf(oacc[dt][2] * inv);
      pk.w = f2bf(oacc[dt][3] * inv);
      *(ushort4*)(ob + l16 * OBS + dt * 16 + quad * 4) = pk;
    }
    __asm__ __volatile__("s_waitcnt lgkmcnt(0)" ::: "memory");
#pragma unroll
    for (int rnd = 0; rnd < 4; ++rnd) {
      int q   = rnd * 4 + (lane >> 4);
      int o8  = lane & 15;
      uint2 d8 = *(const uint2*)(ob + q * OBS + o8 * 4);
      int qrow = mt * 16 + q;
      if (qrow < NTOK) {
        size_t obase = (size_t)(b * NTOK + qrow) * DIMC + h * HDIM;
        *(uint2*)(aout + obase + o8 * 4) = d8;
      }
    }
  }
}

// ---------------- launcher ----------------
extern "C" void kernel_launch(void* const* d_in, const int* in_sizes, int n_in,
                              void* d_out, int out_size, void* d_ws, size_t ws_size,
                              hipStream_t stream) {
  const float* x     = (const float*)d_in[0];
  const float* scale = (const float*)d_in[1];
  const float* wqkv  = (const float*)d_in[2];
  const float* wproj = (const float*)d_in[3];
  const float* bproj = (const float*)d_in[4];
  float* out = (float*)d_out;

  // ws layout (ushort), ~82.2 MB (R6-proven). attb aliases xb.
  unsigned short* xb   = (unsigned short*)d_ws;
  unsigned short* wqb  = xb  + (size_t)MTOK * DIMC;
  unsigned short* wpb  = wqb + (size_t)QKVO * DIMC;
  unsigned short* qkvb = wpb + (size_t)DIMC * DIMC;
  unsigned short* attb = xb;                          // alias

  static bool qkv_attr_set = false;
  if (!qkv_attr_set) {
    hipFuncSetAttribute(reinterpret_cast<const void*>(gemm_qkv),
                        hipFuncAttributeMaxDynamicSharedMemorySize, 131072);
    qkv_attr_set = true;
  }

  cvt_all<<<CVNB, 256, 0, stream>>>(x, wqkv, wproj, xb, wqb, wpb);
  gemm_qkv<<<GM2 * GN2, 512, 131072, stream>>>(xb, wqb, qkvb);
  attn_fused<<<BH, 256, 0, stream>>>(qkvb, scale, attb);
  gemm_proj<<<GM64 * (DIMC / 128), 256, 0, stream>>>(attb, wpb, bproj, x, out);
}